// Round 1
// baseline (470.787 us; speedup 1.0000x reference)
//
#include <hip/hip_runtime.h>
#include <math.h>

#define N_ROWS 8192
#define N_HALF 4096
#define D 128
#define D4 (D / 4)
#define IT 16            // i-rows per block
#define JT 128           // j-rows per LDS chunk
#define PAD_STRIDE 132   // floats per LDS row: 16B-aligned, bank offset 4 per row
#define NTHREADS 256
#define NCHUNKS (N_ROWS / JT)   // 64
#define NBLK (N_ROWS / IT)      // 512

// ---------------- kernel 1: L2-normalize rows of concat(p1, p2) ----------------
__global__ __launch_bounds__(256) void normalize_kernel(
    const float* __restrict__ p1, const float* __restrict__ p2,
    float* __restrict__ z)
{
    const int row = blockIdx.x * 4 + (threadIdx.x >> 6);
    const int lane = threadIdx.x & 63;
    const float* src = (row < N_HALF) ? (p1 + (size_t)row * D)
                                      : (p2 + (size_t)(row - N_HALF) * D);
    float2 v = ((const float2*)src)[lane];
    float ss = v.x * v.x + v.y * v.y;
    #pragma unroll
    for (int m = 1; m < 64; m <<= 1) ss += __shfl_xor(ss, m);
    float norm = fmaxf(sqrtf(ss), 1e-12f);
    float inv = 1.0f / norm;
    float2 o; o.x = v.x * inv; o.y = v.y * inv;
    ((float2*)(z + (size_t)row * D))[lane] = o;
}

// ---------------- kernel 2: fused pairwise exp-rowsum + positive dot ----------------
#define DOT4(acc, va, vb)                                                     \
    acc = fmaf((va).x, (vb).x, acc); acc = fmaf((va).y, (vb).y, acc);         \
    acc = fmaf((va).z, (vb).z, acc); acc = fmaf((va).w, (vb).w, acc)

__global__ __launch_bounds__(256) void simloss_kernel(
    const float* __restrict__ z, float* __restrict__ partials)
{
    __shared__ float Zi[IT * PAD_STRIDE];       // ~8.4 KB
    __shared__ float Zj[JT * PAD_STRIDE];       // ~67.6 KB
    __shared__ float red[IT][33];
    __shared__ float posLds[IT];

    const int t = threadIdx.x;
    const int iBase = blockIdx.x * IT;
    const int ig = t & 7;    // i-group 0..7  -> rows {ig, ig+8}
    const int jg = t >> 3;   // j-group 0..31 -> cols {jg, jg+32, jg+64, jg+96}

    // stage Zi once: 16 rows x 32 float4
    for (int f = t; f < IT * D4; f += NTHREADS) {
        const int r = f >> 5, c = f & 31;
        float4 v = ((const float4*)(z + (size_t)(iBase + r) * D))[c];
        *(float4*)&Zi[r * PAD_STRIDE + c * 4] = v;
    }
    if (t < IT) posLds[t] = 0.0f;

    const int gi0 = iBase + ig;
    const int gi1 = gi0 + 8;
    const int p0 = gi0 ^ N_HALF;
    const int p1 = gi1 ^ N_HALF;

    float acc0 = 0.0f, acc1 = 0.0f;

    for (int chunk = 0; chunk < NCHUNKS; ++chunk) {
        const int jBase = chunk * JT;
        __syncthreads();   // protect Zj from previous iteration's readers
        for (int f = t; f < JT * D4; f += NTHREADS) {
            const int r = f >> 5, c = f & 31;
            float4 v = ((const float4*)(z + (size_t)(jBase + r) * D))[c];
            *(float4*)&Zj[r * PAD_STRIDE + c * 4] = v;
        }
        __syncthreads();

        float d00 = 0, d01 = 0, d02 = 0, d03 = 0;
        float d10 = 0, d11 = 0, d12 = 0, d13 = 0;
        const float* zi0 = &Zi[ig * PAD_STRIDE];
        const float* zi1 = &Zi[(ig + 8) * PAD_STRIDE];
        const float* zj0 = &Zj[jg * PAD_STRIDE];
        const float* zj1 = &Zj[(jg + 32) * PAD_STRIDE];
        const float* zj2 = &Zj[(jg + 64) * PAD_STRIDE];
        const float* zj3 = &Zj[(jg + 96) * PAD_STRIDE];

        #pragma unroll 4
        for (int k4 = 0; k4 < D4; ++k4) {
            const int k = k4 * 4;
            float4 a0 = *(const float4*)(zi0 + k);
            float4 a1 = *(const float4*)(zi1 + k);
            float4 b0 = *(const float4*)(zj0 + k);
            float4 b1 = *(const float4*)(zj1 + k);
            float4 b2 = *(const float4*)(zj2 + k);
            float4 b3 = *(const float4*)(zj3 + k);
            DOT4(d00, a0, b0); DOT4(d01, a0, b1); DOT4(d02, a0, b2); DOT4(d03, a0, b3);
            DOT4(d10, a1, b0); DOT4(d11, a1, b1); DOT4(d12, a1, b2); DOT4(d13, a1, b3);
        }

        int gj = jBase + jg;
        if (gj != gi0) { acc0 += __expf(2.0f * d00); if (gj == p0) posLds[ig]     = d00; }
        if (gj != gi1) { acc1 += __expf(2.0f * d10); if (gj == p1) posLds[ig + 8] = d10; }
        gj += 32;
        if (gj != gi0) { acc0 += __expf(2.0f * d01); if (gj == p0) posLds[ig]     = d01; }
        if (gj != gi1) { acc1 += __expf(2.0f * d11); if (gj == p1) posLds[ig + 8] = d11; }
        gj += 32;
        if (gj != gi0) { acc0 += __expf(2.0f * d02); if (gj == p0) posLds[ig]     = d02; }
        if (gj != gi1) { acc1 += __expf(2.0f * d12); if (gj == p1) posLds[ig + 8] = d12; }
        gj += 32;
        if (gj != gi0) { acc0 += __expf(2.0f * d03); if (gj == p0) posLds[ig]     = d03; }
        if (gj != gi1) { acc1 += __expf(2.0f * d13); if (gj == p1) posLds[ig + 8] = d13; }
    }

    red[ig][jg]     = acc0;
    red[ig + 8][jg] = acc1;
    __syncthreads();

    float loss = 0.0f;
    if (t < IT) {
        float denom = 0.0f;
        #pragma unroll
        for (int g = 0; g < 32; ++g) denom += red[t][g];
        loss = logf(denom) - 2.0f * posLds[t];
    }
    // deterministic block sum: loss lives only in wave 0 lanes 0..15 (others 0)
    if (t < 64) {
        #pragma unroll
        for (int m = 1; m < 64; m <<= 1) loss += __shfl_xor(loss, m);
        if (t == 0) partials[blockIdx.x] = loss * (1.0f / (float)N_ROWS);
    }
}

// ---------------- kernel 3: deterministic final reduce of 512 partials ----------------
__global__ __launch_bounds__(256) void final_reduce(
    const float* __restrict__ partials, float* __restrict__ out)
{
    const int t = threadIdx.x;
    float s = partials[t] + partials[t + 256];
    #pragma unroll
    for (int m = 1; m < 64; m <<= 1) s += __shfl_xor(s, m);
    __shared__ float wsum[4];
    if ((t & 63) == 0) wsum[t >> 6] = s;
    __syncthreads();
    if (t == 0) out[0] = wsum[0] + wsum[1] + wsum[2] + wsum[3];
}

extern "C" void kernel_launch(void* const* d_in, const int* in_sizes, int n_in,
                              void* d_out, int out_size, void* d_ws, size_t ws_size,
                              hipStream_t stream) {
    const float* proj1 = (const float*)d_in[0];
    const float* proj2 = (const float*)d_in[1];
    float* out = (float*)d_out;
    float* z = (float*)d_ws;                       // 8192*128 floats = 4 MB
    float* partials = z + (size_t)N_ROWS * D;      // 512 floats

    normalize_kernel<<<N_ROWS / 4, NTHREADS, 0, stream>>>(proj1, proj2, z);
    simloss_kernel<<<NBLK, NTHREADS, 0, stream>>>(z, partials);
    final_reduce<<<1, NTHREADS, 0, stream>>>(partials, out);
}

// Round 2
// 42.815 us; speedup vs baseline: 10.9959x; 10.9959x over previous
//
#include <hip/hip_runtime.h>
#include <hip/hip_bf16.h>
#include <math.h>

#define N_ROWS 8192
#define N_HALF 4096
#define D 128
#define SEGS 8                  // j-split across blocks
#define IBLKS (N_ROWS / 128)    // 64
#define CHUNKS_PER_SEG ((N_ROWS / SEGS) / 128)  // 8
// scale = sqrt(2 * log2(e)) so that zb_i . zb_j = 2*log2(e)*cos -> exp2(dot) = exp(2*cos)
#define ZSCALE 1.6986437717f

typedef __attribute__((ext_vector_type(8))) short bfrag;   // 8 bf16 = 4 VGPR
typedef __attribute__((ext_vector_type(4))) float f32x4;

__device__ __forceinline__ float fast_exp2(float x) {
#if __has_builtin(__builtin_amdgcn_exp2f)
    return __builtin_amdgcn_exp2f(x);
#else
    return exp2f(x);
#endif
}

// ---------------- kernel 1: normalize rows; emit fp32 z and scaled bf16 z ----------------
__global__ __launch_bounds__(256) void normalize_kernel(
    const float* __restrict__ p1, const float* __restrict__ p2,
    float* __restrict__ zf, ushort* __restrict__ zb)
{
    const int row = blockIdx.x * 4 + (threadIdx.x >> 6);
    const int lane = threadIdx.x & 63;
    const float* src = (row < N_HALF) ? (p1 + (size_t)row * D)
                                      : (p2 + (size_t)(row - N_HALF) * D);
    float2 v = ((const float2*)src)[lane];
    float ss = v.x * v.x + v.y * v.y;
    #pragma unroll
    for (int m = 1; m < 64; m <<= 1) ss += __shfl_xor(ss, m);
    float inv = 1.0f / fmaxf(sqrtf(ss), 1e-12f);
    float2 o; o.x = v.x * inv; o.y = v.y * inv;
    ((float2*)(zf + (size_t)row * D))[lane] = o;
    __hip_bfloat16 h0 = __float2bfloat16(o.x * ZSCALE);
    __hip_bfloat16 h1 = __float2bfloat16(o.y * ZSCALE);
    ushort2 u; u.x = *(ushort*)&h0; u.y = *(ushort*)&h1;
    ((ushort2*)(zb + (size_t)row * D))[lane] = u;
}

// ---------------- kernel 2: fused MFMA Gram + exp2 + row-sum partials ----------------
__global__ __launch_bounds__(256, 2) void simloss_mfma(
    const ushort* __restrict__ zb, float* __restrict__ partial)
{
    __shared__ ushort Bs[128 * 128];   // 32 KB, XOR-swizzled 16B slots
    const int t = threadIdx.x;
    const int w = t >> 6;         // wave 0..3 -> col quarter
    const int l = t & 63;
    const int l15 = l & 15, lh = l >> 4;
    const int bi = blockIdx.x & 63;
    const int seg = blockIdx.x >> 6;
    const int iBase = bi * 128;

    // A tile (128 rows x 128 k) in registers: a[m][ks], one-time global load (L2-resident)
    bfrag a[8][4];
    #pragma unroll
    for (int m = 0; m < 8; ++m) {
        const ushort* rp = zb + (size_t)(iBase + m * 16 + l15) * D;
        #pragma unroll
        for (int ks = 0; ks < 4; ++ks)
            a[m][ks] = *(const bfrag*)(rp + ks * 32 + lh * 8);
    }

    float rs[8][4];
    #pragma unroll
    for (int m = 0; m < 8; ++m)
        #pragma unroll
        for (int r = 0; r < 4; ++r) rs[m][r] = 0.0f;

    for (int ch = 0; ch < CHUNKS_PER_SEG; ++ch) {
        const int jBase = seg * (N_ROWS / SEGS) + ch * 128;
        __syncthreads();   // protect Bs from previous chunk's readers
        // stage B chunk: 2048 16B slots, 8 passes x 256 threads, swizzled write
        #pragma unroll
        for (int p = 0; p < 8; ++p) {
            int s = p * 256 + t;
            int r = s >> 4, c16 = s & 15;
            bfrag v = *(const bfrag*)(zb + (size_t)(jBase + r) * D + c16 * 8);
            int slot = r * 16 + (c16 ^ (r & 7));
            *(bfrag*)(Bs + slot * 8) = v;
        }
        __syncthreads();
        const bool diag = (jBase == iBase);

        #pragma unroll
        for (int n = 0; n < 2; ++n) {
            f32x4 c[8];
            #pragma unroll
            for (int m = 0; m < 8; ++m) { f32x4 z4 = {0.f, 0.f, 0.f, 0.f}; c[m] = z4; }
            const int cB = w * 32 + n * 16 + l15;   // col-in-chunk this lane reads
            #pragma unroll
            for (int ks = 0; ks < 4; ++ks) {
                int k16 = ks * 4 + lh;              // 16B-chunk index within the row
                int slot = cB * 16 + (k16 ^ (cB & 7));
                bfrag b = *(const bfrag*)(Bs + slot * 8);
                #pragma unroll
                for (int m = 0; m < 8; ++m)
                    c[m] = __builtin_amdgcn_mfma_f32_16x16x32_bf16(a[m][ks], b, c[m], 0, 0, 0);
            }
            if (diag) {
                const int colLocal = cB;
                #pragma unroll
                for (int m = 0; m < 8; ++m)
                    #pragma unroll
                    for (int r = 0; r < 4; ++r) {
                        int rowLocal = m * 16 + lh * 4 + r;
                        float e = fast_exp2(c[m][r]);
                        rs[m][r] += (rowLocal == colLocal) ? 0.0f : e;
                    }
            } else {
                #pragma unroll
                for (int m = 0; m < 8; ++m)
                    #pragma unroll
                    for (int r = 0; r < 4; ++r)
                        rs[m][r] += fast_exp2(c[m][r]);
            }
        }
    }

    // reduce over the 16 cols held across lanes (same row group shares lh)
    #pragma unroll
    for (int m = 0; m < 8; ++m)
        #pragma unroll
        for (int r = 0; r < 4; ++r) {
            float v = rs[m][r];
            v += __shfl_xor(v, 1); v += __shfl_xor(v, 2);
            v += __shfl_xor(v, 4); v += __shfl_xor(v, 8);
            rs[m][r] = v;
        }
    __syncthreads();                 // done reading Bs; reuse as reduce buffer
    float* red = (float*)Bs;         // [128 rows][4 waves]
    if (l15 == 0) {
        #pragma unroll
        for (int m = 0; m < 8; ++m)
            #pragma unroll
            for (int r = 0; r < 4; ++r)
                red[(m * 16 + lh * 4 + r) * 4 + w] = rs[m][r];
    }
    __syncthreads();
    if (t < 128) {
        float v = red[t * 4 + 0] + red[t * 4 + 1] + red[t * 4 + 2] + red[t * 4 + 3];
        partial[(size_t)seg * N_ROWS + iBase + t] = v;
    }
}

// ---------------- kernel 3: exact fp32 positive dots ----------------
__global__ __launch_bounds__(256) void pos_kernel(
    const float* __restrict__ zf, float* __restrict__ pos)
{
    const int row = blockIdx.x * 4 + (threadIdx.x >> 6);
    const int lane = threadIdx.x & 63;
    float2 x = ((const float2*)(zf + (size_t)row * D))[lane];
    float2 y = ((const float2*)(zf + (size_t)(row ^ N_HALF) * D))[lane];
    float d = x.x * y.x + x.y * y.y;
    #pragma unroll
    for (int m = 1; m < 64; m <<= 1) d += __shfl_xor(d, m);
    if (lane == 0) pos[row] = d;
}

// ---------------- kernel 4: per-row loss + per-block deterministic sum ----------------
__global__ __launch_bounds__(256) void rowloss_kernel(
    const float* __restrict__ partial, const float* __restrict__ pos,
    float* __restrict__ bsum)
{
    const int row = blockIdx.x * 256 + threadIdx.x;
    float denom = 0.0f;
    #pragma unroll
    for (int s = 0; s < SEGS; ++s) denom += partial[(size_t)s * N_ROWS + row];
    float loss = logf(denom) - 2.0f * pos[row];
    #pragma unroll
    for (int m = 1; m < 64; m <<= 1) loss += __shfl_xor(loss, m);
    __shared__ float red[4];
    if ((threadIdx.x & 63) == 0) red[threadIdx.x >> 6] = loss;
    __syncthreads();
    if (threadIdx.x == 0) bsum[blockIdx.x] = red[0] + red[1] + red[2] + red[3];
}

// ---------------- kernel 5: final deterministic reduce of 32 block sums ----------------
__global__ __launch_bounds__(64) void final_reduce(
    const float* __restrict__ bsum, float* __restrict__ out)
{
    const int t = threadIdx.x;
    float s = (t < 32) ? bsum[t] : 0.0f;
    #pragma unroll
    for (int m = 1; m < 64; m <<= 1) s += __shfl_xor(s, m);
    if (t == 0) out[0] = s * (1.0f / (float)N_ROWS);
}

extern "C" void kernel_launch(void* const* d_in, const int* in_sizes, int n_in,
                              void* d_out, int out_size, void* d_ws, size_t ws_size,
                              hipStream_t stream) {
    const float* proj1 = (const float*)d_in[0];
    const float* proj2 = (const float*)d_in[1];
    float* out = (float*)d_out;

    char* ws = (char*)d_ws;
    float*  zf      = (float*)ws;                                  // 4 MB
    ushort* zb      = (ushort*)(ws + (size_t)4 * 1024 * 1024);     // 2 MB
    float*  partial = (float*)(ws + (size_t)6 * 1024 * 1024);      // 256 KB
    float*  pos     = (float*)(ws + (size_t)6 * 1024 * 1024 + 512 * 1024);  // 32 KB
    float*  bsum    = (float*)(ws + (size_t)6 * 1024 * 1024 + 768 * 1024);  // 128 B

    normalize_kernel<<<N_ROWS / 4, 256, 0, stream>>>(proj1, proj2, zf, zb);
    simloss_mfma<<<IBLKS * SEGS, 256, 0, stream>>>(zb, partial);
    pos_kernel<<<N_ROWS / 4, 256, 0, stream>>>(zf, pos);
    rowloss_kernel<<<N_ROWS / 256, 256, 0, stream>>>(partial, pos, bsum);
    final_reduce<<<1, 64, 0, stream>>>(bsum, out);
}